// Round 1
// baseline (444.539 us; speedup 1.0000x reference)
//
#include <hip/hip_runtime.h>
#include <hip/hip_bf16.h>

#define N 8192
#define DIN 128
#define DHID 256
#define DOUT 64
#define LDP 72  // padded LDS row stride (ushorts): 144B -> 4-bank step per row

typedef __attribute__((ext_vector_type(8))) short short8;
typedef __attribute__((ext_vector_type(4))) float f32x4;
typedef __attribute__((ext_vector_type(4))) unsigned short u16x4;

__device__ inline unsigned short f2bf(float x) {
  unsigned u = __float_as_uint(x);
  u += 0x7FFF + ((u >> 16) & 1);   // RNE
  return (unsigned short)(u >> 16);
}

__device__ inline float sig_clip(float x) {
  float s = 1.0f / (1.0f + __expf(-x));
  return fmaxf(s, 0.1f);
}

// ---------------- K1: BatchNorm statistics ----------------
__global__ void bn_stats(const float* __restrict__ H, const float* __restrict__ bnw,
                         const float* __restrict__ bnb, float* __restrict__ scale,
                         float* __restrict__ shift) {
  int f = blockIdx.x;
  int t = threadIdx.x;
  float s = 0.f, sq = 0.f;
  for (int r = t; r < N; r += 256) {
    float v = H[(size_t)r * DIN + f];
    s += v; sq += v * v;
  }
  __shared__ float ss[256], s2[256];
  ss[t] = s; s2[t] = sq;
  __syncthreads();
  for (int o = 128; o > 0; o >>= 1) {
    if (t < o) { ss[t] += ss[t + o]; s2[t] += s2[t + o]; }
    __syncthreads();
  }
  if (t == 0) {
    float mean = ss[0] * (1.0f / N);
    float var = s2[0] * (1.0f / N) - mean * mean;
    float sc = rsqrtf(var + 1e-5f) * bnw[f];
    scale[f] = sc;
    shift[f] = bnb[f] - mean * sc;
  }
}

// ---------------- K2: Hn (on the fly) -> Hx bf16 [N,256], M2 bf16 [N,64] ----------------
__global__ __launch_bounds__(256) void proj(const float* __restrict__ H,
                     const float* __restrict__ scale, const float* __restrict__ shift,
                     const float* __restrict__ Wt, const float* __restrict__ bt,
                     const float* __restrict__ Wo, const float* __restrict__ bo,
                     unsigned short* __restrict__ Hx, unsigned short* __restrict__ M2) {
  __shared__ float hn[8][DIN];
  int i0 = blockIdx.x * 8;
  int t = threadIdx.x;
  #pragma unroll
  for (int rep = 0; rep < 4; ++rep) {
    int idx = rep * 256 + t;
    int r = idx >> 7, c = idx & 127;
    float h = H[(size_t)(i0 + r) * DIN + c];
    hn[r][c] = fmaf(h, scale[c], shift[c]);
  }
  __syncthreads();
  {
    int c = t;  // 0..255
    float acc[8];
    float b = bt[c];
    #pragma unroll
    for (int r = 0; r < 8; ++r) acc[r] = b;
    for (int k = 0; k < DIN; ++k) {
      float w = Wt[k * DHID + c];
      #pragma unroll
      for (int r = 0; r < 8; ++r) acc[r] = fmaf(hn[r][k], w, acc[r]);
    }
    #pragma unroll
    for (int r = 0; r < 8; ++r) Hx[(size_t)(i0 + r) * DHID + c] = f2bf(acc[r]);
  }
  if (t < DOUT) {
    int c = t;
    float acc[8];
    float b = bo[c];
    #pragma unroll
    for (int r = 0; r < 8; ++r) acc[r] = b;
    for (int k = 0; k < DIN; ++k) {
      float w = Wo[k * DOUT + c];
      #pragma unroll
      for (int r = 0; r < 8; ++r) acc[r] = fmaf(hn[r][k], w, acc[r]);
    }
    #pragma unroll
    for (int r = 0; r < 8; ++r) M2[(size_t)(i0 + r) * DOUT + c] = f2bf(acc[r]);
  }
}

// ---------------- K3: S = sigmoid(Hx Hx^T) tiles; PASS 1 = rowsums, PASS 2 = A_hat ----------------
template <int PASS>
__global__ __launch_bounds__(256) void smat(const unsigned short* __restrict__ Hx,
                     const float* __restrict__ A, const float* __restrict__ dd,
                     float* __restrict__ rowsum, float* __restrict__ Ahat) {
  __shared__ unsigned short la[128][LDP];
  __shared__ unsigned short lb[128][LDP];
  __shared__ float sddj[128];
  int jt = blockIdx.x, it = blockIdx.y;
  int i0 = it * 128, j0 = jt * 128;
  int t = threadIdx.x;
  int w = t >> 6, l = t & 63;
  int lr = l & 15, lg = l >> 4;

  f32x4 acc[2][8];
  f32x4 zero = {0.f, 0.f, 0.f, 0.f};
  #pragma unroll
  for (int m = 0; m < 2; ++m)
    #pragma unroll
    for (int n = 0; n < 8; ++n) acc[m][n] = zero;

  for (int c4 = 0; c4 < 4; ++c4) {
    int k0 = c4 * 64;
    __syncthreads();
    #pragma unroll
    for (int rp = 0; rp < 4; ++rp) {
      int row = rp * 32 + (t >> 3);
      int ch = (t & 7) * 8;
      *(short8*)&la[row][ch] = *(const short8*)&Hx[(size_t)(i0 + row) * DHID + k0 + ch];
      *(short8*)&lb[row][ch] = *(const short8*)&Hx[(size_t)(j0 + row) * DHID + k0 + ch];
    }
    __syncthreads();
    #pragma unroll
    for (int kk = 0; kk < 2; ++kk) {
      short8 af[2], bf[8];
      #pragma unroll
      for (int m = 0; m < 2; ++m)
        af[m] = *(const short8*)&la[w * 32 + m * 16 + lr][kk * 32 + lg * 8];
      #pragma unroll
      for (int n = 0; n < 8; ++n)
        bf[n] = *(const short8*)&lb[n * 16 + lr][kk * 32 + lg * 8];
      #pragma unroll
      for (int m = 0; m < 2; ++m)
        #pragma unroll
        for (int n = 0; n < 8; ++n)
          acc[m][n] = __builtin_amdgcn_mfma_f32_16x16x32_bf16(af[m], bf[n], acc[m][n], 0, 0, 0);
    }
  }

  if (PASS == 2) {
    __syncthreads();
    if (t < 128) sddj[t] = dd[j0 + t];
    __syncthreads();
  }

  #pragma unroll
  for (int m = 0; m < 2; ++m) {
    #pragma unroll
    for (int r = 0; r < 4; ++r) {
      int gi = i0 + w * 32 + m * 16 + lg * 4 + r;
      if (PASS == 1) {
        float part = 0.f;
        #pragma unroll
        for (int n = 0; n < 8; ++n) {
          int gj = j0 + n * 16 + lr;
          float a = A[(size_t)gi * N + gj];
          float v = sig_clip(acc[m][n][r]) * (a > 0.f ? 1.f : 0.f) + (gi == gj ? 1.f : 0.f);
          part += v;
        }
        part += __shfl_xor(part, 1);
        part += __shfl_xor(part, 2);
        part += __shfl_xor(part, 4);
        part += __shfl_xor(part, 8);
        if (lr == 0) atomicAdd(&rowsum[gi], part);
      } else {
        float di = dd[gi];
        #pragma unroll
        for (int n = 0; n < 8; ++n) {
          int gj = j0 + n * 16 + lr;
          float a = A[(size_t)gi * N + gj];
          float v = sig_clip(acc[m][n][r]) * (a > 0.f ? 1.f : 0.f) + (gi == gj ? 1.f : 0.f);
          Ahat[(size_t)gi * N + gj] = v * di * sddj[n * 16 + lr];
        }
      }
    }
  }
}

// ---------------- K3b: d = rsqrt(rowsum), in place ----------------
__global__ void dfin(float* rs) {
  int i = blockIdx.x * 256 + threadIdx.x;
  if (i < N) rs[i] = rsqrtf(rs[i]);
}

// ---------------- K4: out = A_hat @ M2 (bf16 MFMA), k-split with atomics ----------------
__global__ __launch_bounds__(256) void outmm(const float* __restrict__ Ahat,
                      const unsigned short* __restrict__ M2, float* __restrict__ out) {
  __shared__ unsigned short la[128][LDP];
  __shared__ unsigned short lbT[64][LDP];
  int kc = blockIdx.x;   // 0..7  (j-chunk of 1024)
  int it = blockIdx.y;   // 0..63 (i-tile of 128)
  int i0 = it * 128;
  int jbase = kc * 1024;
  int t = threadIdx.x;
  int w = t >> 6, l = t & 63;
  int lr = l & 15, lg = l >> 4;

  f32x4 acc[2][4];
  f32x4 zero = {0.f, 0.f, 0.f, 0.f};
  #pragma unroll
  for (int m = 0; m < 2; ++m)
    #pragma unroll
    for (int n = 0; n < 4; ++n) acc[m][n] = zero;

  for (int s = 0; s < 16; ++s) {
    int j0 = jbase + s * 64;
    __syncthreads();
    // stage A_hat f32 -> bf16 LDS
    #pragma unroll
    for (int rep = 0; rep < 8; ++rep) {
      int row = rep * 16 + (t >> 4);
      int cc = (t & 15) * 4;
      f32x4 v = *(const f32x4*)&Ahat[(size_t)(i0 + row) * N + j0 + cc];
      u16x4 b;
      b[0] = f2bf(v[0]); b[1] = f2bf(v[1]); b[2] = f2bf(v[2]); b[3] = f2bf(v[3]);
      *(u16x4*)&la[row][cc] = b;
    }
    // stage M2 transposed: lbT[c][k]
    #pragma unroll
    for (int rep = 0; rep < 2; ++rep) {
      int idx = rep * 256 + t;  // 0..511
      int row = idx >> 3;       // k local 0..63
      int ch = (idx & 7) * 8;   // col chunk
      short8 v = *(const short8*)&M2[(size_t)(j0 + row) * DOUT + ch];
      #pragma unroll
      for (int e = 0; e < 8; ++e) lbT[ch + e][row] = (unsigned short)v[e];
    }
    __syncthreads();
    #pragma unroll
    for (int kk = 0; kk < 2; ++kk) {
      short8 af[2], bf[4];
      #pragma unroll
      for (int m = 0; m < 2; ++m)
        af[m] = *(const short8*)&la[w * 32 + m * 16 + lr][kk * 32 + lg * 8];
      #pragma unroll
      for (int n = 0; n < 4; ++n)
        bf[n] = *(const short8*)&lbT[n * 16 + lr][kk * 32 + lg * 8];
      #pragma unroll
      for (int m = 0; m < 2; ++m)
        #pragma unroll
        for (int n = 0; n < 4; ++n)
          acc[m][n] = __builtin_amdgcn_mfma_f32_16x16x32_bf16(af[m], bf[n], acc[m][n], 0, 0, 0);
    }
  }
  #pragma unroll
  for (int m = 0; m < 2; ++m)
    #pragma unroll
    for (int n = 0; n < 4; ++n)
      #pragma unroll
      for (int r = 0; r < 4; ++r) {
        int gi = i0 + w * 32 + m * 16 + lg * 4 + r;
        int gc = n * 16 + lr;
        atomicAdd(&out[(size_t)gi * DOUT + gc], acc[m][n][r]);
      }
}

// ---------------- K5: LeakyReLU on out ----------------
__global__ void leaky(float* out) {
  int i = blockIdx.x * 256 + threadIdx.x;
  if (i < N * DOUT) {
    float x = out[i];
    out[i] = x >= 0.f ? x : 0.01f * x;
  }
}

extern "C" void kernel_launch(void* const* d_in, const int* in_sizes, int n_in,
                              void* d_out, int out_size, void* d_ws, size_t ws_size,
                              hipStream_t stream) {
  const float* H   = (const float*)d_in[0];
  const float* A   = (const float*)d_in[1];
  const float* bnw = (const float*)d_in[2];
  const float* bnb = (const float*)d_in[3];
  const float* Wt  = (const float*)d_in[4];
  const float* bt  = (const float*)d_in[5];
  const float* Wo  = (const float*)d_in[6];
  const float* bo  = (const float*)d_in[7];
  float* out = (float*)d_out;
  float* Ahat = out + (size_t)N * DOUT;

  char* ws = (char*)d_ws;
  float* scale  = (float*)(ws + 0);
  float* shift  = (float*)(ws + 512);
  float* rowsum = (float*)(ws + 4096);                   // 32 KB, becomes d after dfin
  unsigned short* M2 = (unsigned short*)(ws + 65536);    // 1 MB
  unsigned short* Hx = (unsigned short*)(ws + 2097152);  // 4 MB

  hipMemsetAsync(rowsum, 0, N * sizeof(float), stream);
  hipMemsetAsync(out, 0, (size_t)N * DOUT * sizeof(float), stream);

  bn_stats<<<DIN, 256, 0, stream>>>(H, bnw, bnb, scale, shift);
  proj<<<N / 8, 256, 0, stream>>>(H, scale, shift, Wt, bt, Wo, bo, Hx, M2);
  smat<1><<<dim3(64, 64), 256, 0, stream>>>(Hx, A, nullptr, rowsum, nullptr);
  dfin<<<N / 256, 256, 0, stream>>>(rowsum);
  smat<2><<<dim3(64, 64), 256, 0, stream>>>(Hx, A, rowsum, nullptr, Ahat);
  outmm<<<dim3(8, 64), 256, 0, stream>>>(Ahat, M2, out);
  leaky<<<(N * DOUT + 255) / 256, 256, 0, stream>>>(out);
}

// Round 2
// 377.244 us; speedup vs baseline: 1.1784x; 1.1784x over previous
//
#include <hip/hip_runtime.h>
#include <hip/hip_bf16.h>

#define N 8192
#define DIN 128
#define DHID 256
#define DOUT 64
#define LDP 72  // padded LDS row stride (ushorts): 144B -> 4-bank step per row

typedef __attribute__((ext_vector_type(8))) short short8;
typedef __attribute__((ext_vector_type(4))) float f32x4;
typedef __attribute__((ext_vector_type(4))) unsigned short u16x4;

__device__ inline unsigned short f2bf(float x) {
  unsigned u = __float_as_uint(x);
  u += 0x7FFF + ((u >> 16) & 1);   // RNE
  return (unsigned short)(u >> 16);
}
__device__ inline float bf2f(unsigned short u) {
  return __uint_as_float(((unsigned)u) << 16);
}
__device__ inline float sig_clip(float x) {
  float s = 1.0f / (1.0f + __expf(-x));
  return fmaxf(s, 0.1f);
}

// ---------------- K1: BatchNorm statistics ----------------
__global__ void bn_stats(const float* __restrict__ H, const float* __restrict__ bnw,
                         const float* __restrict__ bnb, float* __restrict__ scale,
                         float* __restrict__ shift) {
  int f = blockIdx.x;
  int t = threadIdx.x;
  float s = 0.f, sq = 0.f;
  for (int r = t; r < N; r += 256) {
    float v = H[(size_t)r * DIN + f];
    s += v; sq += v * v;
  }
  __shared__ float ss[256], s2[256];
  ss[t] = s; s2[t] = sq;
  __syncthreads();
  for (int o = 128; o > 0; o >>= 1) {
    if (t < o) { ss[t] += ss[t + o]; s2[t] += s2[t + o]; }
    __syncthreads();
  }
  if (t == 0) {
    float mean = ss[0] * (1.0f / N);
    float var = s2[0] * (1.0f / N) - mean * mean;
    float sc = rsqrtf(var + 1e-5f) * bnw[f];
    scale[f] = sc;
    shift[f] = bnb[f] - mean * sc;
  }
}

// ---------------- K2: Hn (on the fly) -> Hx bf16 [N,256], M2 bf16 [N,64] ----------------
__global__ __launch_bounds__(256) void proj(const float* __restrict__ H,
                     const float* __restrict__ scale, const float* __restrict__ shift,
                     const float* __restrict__ Wt, const float* __restrict__ bt,
                     const float* __restrict__ Wo, const float* __restrict__ bo,
                     unsigned short* __restrict__ Hx, unsigned short* __restrict__ M2) {
  __shared__ float hn[8][DIN];
  int i0 = blockIdx.x * 8;
  int t = threadIdx.x;
  #pragma unroll
  for (int rep = 0; rep < 4; ++rep) {
    int idx = rep * 256 + t;
    int r = idx >> 7, c = idx & 127;
    float h = H[(size_t)(i0 + r) * DIN + c];
    hn[r][c] = fmaf(h, scale[c], shift[c]);
  }
  __syncthreads();
  {
    int c = t;  // 0..255
    float acc[8];
    float b = bt[c];
    #pragma unroll
    for (int r = 0; r < 8; ++r) acc[r] = b;
    for (int k = 0; k < DIN; ++k) {
      float w = Wt[k * DHID + c];
      #pragma unroll
      for (int r = 0; r < 8; ++r) acc[r] = fmaf(hn[r][k], w, acc[r]);
    }
    #pragma unroll
    for (int r = 0; r < 8; ++r) Hx[(size_t)(i0 + r) * DHID + c] = f2bf(acc[r]);
  }
  if (t < DOUT) {
    int c = t;
    float acc[8];
    float b = bo[c];
    #pragma unroll
    for (int r = 0; r < 8; ++r) acc[r] = b;
    for (int k = 0; k < DIN; ++k) {
      float w = Wo[k * DOUT + c];
      #pragma unroll
      for (int r = 0; r < 8; ++r) acc[r] = fmaf(hn[r][k], w, acc[r]);
    }
    #pragma unroll
    for (int r = 0; r < 8; ++r) M2[(size_t)(i0 + r) * DOUT + c] = f2bf(acc[r]);
  }
}

// ---------------- K3: single pass: v = clip(sig(Hx Hx^T))*mask + I ----------------
// Writes unscaled v (bf16 to ws, or f32 to Ahat region) + row sums.
template <int BF16V>
__global__ __launch_bounds__(256) void smat(const unsigned short* __restrict__ Hx,
                     const float* __restrict__ A,
                     float* __restrict__ rowsum,
                     void* __restrict__ Vout) {
  __shared__ unsigned short la[128][LDP];
  __shared__ unsigned short lb[128][LDP];
  int jt = blockIdx.x, it = blockIdx.y;
  int i0 = it * 128, j0 = jt * 128;
  int t = threadIdx.x;
  int w = t >> 6, l = t & 63;
  int lr = l & 15, lg = l >> 4;

  // --- A-mask preload -> 64-bit register bitmask (latency overlaps the K-loop) ---
  unsigned um[2] = {0u, 0u};
  #pragma unroll
  for (int m = 0; m < 2; ++m) {
    #pragma unroll
    for (int r = 0; r < 4; ++r) {
      int gi = i0 + w * 32 + m * 16 + lg * 4 + r;
      const float* Arow = &A[(size_t)gi * N + j0 + lr];
      #pragma unroll
      for (int n = 0; n < 8; ++n) {
        float a = Arow[n * 16];
        um[m] |= (a > 0.f ? 1u : 0u) << (r * 8 + n);
      }
    }
  }

  f32x4 acc[2][8];
  f32x4 zero = {0.f, 0.f, 0.f, 0.f};
  #pragma unroll
  for (int m = 0; m < 2; ++m)
    #pragma unroll
    for (int n = 0; n < 8; ++n) acc[m][n] = zero;

  for (int c4 = 0; c4 < 4; ++c4) {
    int k0 = c4 * 64;
    __syncthreads();
    #pragma unroll
    for (int rp = 0; rp < 4; ++rp) {
      int row = rp * 32 + (t >> 3);
      int ch = (t & 7) * 8;
      *(short8*)&la[row][ch] = *(const short8*)&Hx[(size_t)(i0 + row) * DHID + k0 + ch];
      *(short8*)&lb[row][ch] = *(const short8*)&Hx[(size_t)(j0 + row) * DHID + k0 + ch];
    }
    __syncthreads();
    #pragma unroll
    for (int kk = 0; kk < 2; ++kk) {
      short8 af[2], bf[8];
      #pragma unroll
      for (int m = 0; m < 2; ++m)
        af[m] = *(const short8*)&la[w * 32 + m * 16 + lr][kk * 32 + lg * 8];
      #pragma unroll
      for (int n = 0; n < 8; ++n)
        bf[n] = *(const short8*)&lb[n * 16 + lr][kk * 32 + lg * 8];
      #pragma unroll
      for (int m = 0; m < 2; ++m)
        #pragma unroll
        for (int n = 0; n < 8; ++n)
          acc[m][n] = __builtin_amdgcn_mfma_f32_16x16x32_bf16(af[m], bf[n], acc[m][n], 0, 0, 0);
    }
  }

  #pragma unroll
  for (int m = 0; m < 2; ++m) {
    #pragma unroll
    for (int r = 0; r < 4; ++r) {
      int gi = i0 + w * 32 + m * 16 + lg * 4 + r;
      float part = 0.f;
      #pragma unroll
      for (int n = 0; n < 8; ++n) {
        int gj = j0 + n * 16 + lr;
        float ms = ((um[m] >> (r * 8 + n)) & 1u) ? 1.f : 0.f;
        float v = sig_clip(acc[m][n][r]) * ms + (gi == gj ? 1.f : 0.f);
        part += v;
        if (BF16V)
          ((unsigned short*)Vout)[(size_t)gi * N + gj] = f2bf(v);
        else
          ((float*)Vout)[(size_t)gi * N + gj] = v;
      }
      part += __shfl_xor(part, 1);
      part += __shfl_xor(part, 2);
      part += __shfl_xor(part, 4);
      part += __shfl_xor(part, 8);
      if (lr == 0) atomicAdd(&rowsum[gi], part);
    }
  }
}

// ---------------- K3b: d = rsqrt(rowsum), in place ----------------
__global__ void dfin(float* rs) {
  int i = blockIdx.x * 256 + threadIdx.x;
  if (i < N) rs[i] = rsqrtf(rs[i]);
}

// ---------------- K4: fused scale + A_hat write + out = A_hat @ M2 ----------------
template <int BF16V>
__global__ __launch_bounds__(256) void outmm(const void* __restrict__ Vin,
                      const float* __restrict__ dd,
                      const unsigned short* __restrict__ M2,
                      float* __restrict__ Ahat, float* __restrict__ out) {
  __shared__ unsigned short la[128][LDP];
  __shared__ unsigned short lbT[64][LDP];
  int kc = blockIdx.x;   // 0..7  (j-chunk of 1024)
  int it = blockIdx.y;   // 0..63 (i-tile of 128)
  int i0 = it * 128;
  int jbase = kc * 1024;
  int t = threadIdx.x;
  int w = t >> 6, l = t & 63;
  int lr = l & 15, lg = l >> 4;

  f32x4 acc[2][4];
  f32x4 zero = {0.f, 0.f, 0.f, 0.f};
  #pragma unroll
  for (int m = 0; m < 2; ++m)
    #pragma unroll
    for (int n = 0; n < 4; ++n) acc[m][n] = zero;

  for (int s = 0; s < 16; ++s) {
    int j0 = jbase + s * 64;
    __syncthreads();
    // stage v -> scale by di*dj -> write final f32 A_hat -> bf16 LDS
    #pragma unroll
    for (int rep = 0; rep < 8; ++rep) {
      int row = rep * 16 + (t >> 4);
      int cc = (t & 15) * 4;
      size_t idx = (size_t)(i0 + row) * N + j0 + cc;
      f32x4 v;
      if (BF16V) {
        u16x4 u = *(const u16x4*)&((const unsigned short*)Vin)[idx];
        v[0] = bf2f(u[0]); v[1] = bf2f(u[1]); v[2] = bf2f(u[2]); v[3] = bf2f(u[3]);
      } else {
        v = *(const f32x4*)&((const float*)Vin)[idx];
      }
      float di = dd[i0 + row];
      f32x4 dj = *(const f32x4*)&dd[j0 + cc];
      f32x4 sv;
      sv[0] = v[0] * di * dj[0]; sv[1] = v[1] * di * dj[1];
      sv[2] = v[2] * di * dj[2]; sv[3] = v[3] * di * dj[3];
      *(f32x4*)&Ahat[idx] = sv;
      u16x4 b;
      b[0] = f2bf(sv[0]); b[1] = f2bf(sv[1]); b[2] = f2bf(sv[2]); b[3] = f2bf(sv[3]);
      *(u16x4*)&la[row][cc] = b;
    }
    // stage M2 transposed: lbT[c][k]
    #pragma unroll
    for (int rep = 0; rep < 2; ++rep) {
      int idx = rep * 256 + t;  // 0..511
      int row = idx >> 3;       // k local 0..63
      int ch = (idx & 7) * 8;   // col chunk
      short8 v = *(const short8*)&M2[(size_t)(j0 + row) * DOUT + ch];
      #pragma unroll
      for (int e = 0; e < 8; ++e) lbT[ch + e][row] = (unsigned short)v[e];
    }
    __syncthreads();
    #pragma unroll
    for (int kk = 0; kk < 2; ++kk) {
      short8 af[2], bf[4];
      #pragma unroll
      for (int m = 0; m < 2; ++m)
        af[m] = *(const short8*)&la[w * 32 + m * 16 + lr][kk * 32 + lg * 8];
      #pragma unroll
      for (int n = 0; n < 4; ++n)
        bf[n] = *(const short8*)&lbT[n * 16 + lr][kk * 32 + lg * 8];
      #pragma unroll
      for (int m = 0; m < 2; ++m)
        #pragma unroll
        for (int n = 0; n < 4; ++n)
          acc[m][n] = __builtin_amdgcn_mfma_f32_16x16x32_bf16(af[m], bf[n], acc[m][n], 0, 0, 0);
    }
  }
  #pragma unroll
  for (int m = 0; m < 2; ++m)
    #pragma unroll
    for (int n = 0; n < 4; ++n)
      #pragma unroll
      for (int r = 0; r < 4; ++r) {
        int gi = i0 + w * 32 + m * 16 + lg * 4 + r;
        int gc = n * 16 + lr;
        atomicAdd(&out[(size_t)gi * DOUT + gc], acc[m][n][r]);
      }
}

// ---------------- K5: LeakyReLU on out ----------------
__global__ void leaky(float* out) {
  int i = blockIdx.x * 256 + threadIdx.x;
  if (i < N * DOUT) {
    float x = out[i];
    out[i] = x >= 0.f ? x : 0.01f * x;
  }
}

extern "C" void kernel_launch(void* const* d_in, const int* in_sizes, int n_in,
                              void* d_out, int out_size, void* d_ws, size_t ws_size,
                              hipStream_t stream) {
  const float* H   = (const float*)d_in[0];
  const float* A   = (const float*)d_in[1];
  const float* bnw = (const float*)d_in[2];
  const float* bnb = (const float*)d_in[3];
  const float* Wt  = (const float*)d_in[4];
  const float* bt  = (const float*)d_in[5];
  const float* Wo  = (const float*)d_in[6];
  const float* bo  = (const float*)d_in[7];
  float* out = (float*)d_out;
  float* Ahat = out + (size_t)N * DOUT;

  char* ws = (char*)d_ws;
  float* scale  = (float*)(ws + 0);
  float* shift  = (float*)(ws + 512);
  float* rowsum = (float*)(ws + 4096);                   // 32 KB, becomes d after dfin
  unsigned short* M2 = (unsigned short*)(ws + 65536);    // 1 MB slot
  unsigned short* Hx = (unsigned short*)(ws + 2097152);  // 4 MB slot
  unsigned short* Vbf = (unsigned short*)(ws + (size_t)(8u << 20));  // 134 MB slot

  const size_t need_bf16 = (size_t)(8u << 20) + (size_t)N * N * 2;
  const bool big = ws_size >= need_bf16;

  hipMemsetAsync(rowsum, 0, N * sizeof(float), stream);
  hipMemsetAsync(out, 0, (size_t)N * DOUT * sizeof(float), stream);

  bn_stats<<<DIN, 256, 0, stream>>>(H, bnw, bnb, scale, shift);
  proj<<<N / 8, 256, 0, stream>>>(H, scale, shift, Wt, bt, Wo, bo, Hx, M2);
  if (big) {
    smat<1><<<dim3(64, 64), 256, 0, stream>>>(Hx, A, rowsum, (void*)Vbf);
    dfin<<<N / 256, 256, 0, stream>>>(rowsum);
    outmm<1><<<dim3(8, 64), 256, 0, stream>>>((const void*)Vbf, rowsum, M2, Ahat, out);
  } else {
    smat<0><<<dim3(64, 64), 256, 0, stream>>>(Hx, A, rowsum, (void*)Ahat);
    dfin<<<N / 256, 256, 0, stream>>>(rowsum);
    outmm<0><<<dim3(8, 64), 256, 0, stream>>>((const void*)Ahat, rowsum, M2, Ahat, out);
  }
  leaky<<<(N * DOUT + 255) / 256, 256, 0, stream>>>(out);
}